// Round 6
// baseline (244.143 us; speedup 1.0000x reference)
//
#include <hip/hip_runtime.h>
#include <hip/hip_bf16.h>

// WindowAttention — r10: clean test of 2-independent-blocks/CU.
//   r8/r9 both spilled (unified VGPR+AGPR demand > 256 budget under
//   __launch_bounds__(256,2): VGPR_Count pinned at 128 + 80-250 MB scratch).
//   Changes vs r9, same skeleton (256 thr / 4 waves, wave = 2 heads,
//   8KB wave-private stripes, 2 barriers, 69.6 KB LDS):
//     - __launch_bounds__(256) only: no occupancy demand -> allocator takes
//       what it needs; 2 blocks/CU falls out if allocation <= 256.
//     - Q-pass then K-pass (32 accs live each, was 64 fused).
//     - S/softmax/P/PV fused per ct-pair: S[4][2] live (32 regs, was 64).
//   Pass/fail: FETCH ~66 MB, WRITE ~66 MB (no scratch). If clean but
//   >=140 us, independent-block theory is refuted.

using short8  = __attribute__((ext_vector_type(8))) short;
using short4v = __attribute__((ext_vector_type(4))) short;
using floatx4 = __attribute__((ext_vector_type(4))) float;
using uint4v  = __attribute__((ext_vector_type(4))) unsigned int;

#define PI_F    3.14159265358979323846f
#define SCALE_F 0.17677669529663687f   // 32^-0.5

__device__ __forceinline__ short bfs(float x) {
  __hip_bfloat16 h = __float2bfloat16(x);
  return __builtin_bit_cast(short, h);
}

__device__ __forceinline__ unsigned pk2(float a, float b) {
  unsigned lo = (unsigned short)bfs(a);
  unsigned hi = (unsigned short)bfs(b);
  return lo | (hi << 16);
}

// ---------------- kernel 1: weights fp32 -> bf16 into ws ----------------
__global__ void prep_kernel(const float* __restrict__ qw,
                            const float* __restrict__ pw,
                            __hip_bfloat16* __restrict__ dst) {
  int g = blockIdx.x * 256 + threadIdx.x;  // 65536 threads, one float4 each
  const float4* src;
  __hip_bfloat16* d;
  if (g < 49152) { src = (const float4*)qw + g; d = dst + g * 4; }
  else { int g2 = g - 49152; src = (const float4*)pw + g2; d = dst + 196608 + g2 * 4; }
  float4 v = *src;
  d[0] = __float2bfloat16(v.x);
  d[1] = __float2bfloat16(v.y);
  d[2] = __float2bfloat16(v.z);
  d[3] = __float2bfloat16(v.w);
}

__device__ __forceinline__ void fourier_feats(float dv, int col, float* f) {
  float s1, c1; __sincosf(PI_F * dv, &s1, &c1);
  float c2 = c1*c1 - s1*s1, s2 = 2.f*s1*c1;
  float c3 = c2*c1 - s2*s1, s3 = s2*c1 + c2*s1;
  float c4 = c2*c2 - s2*s2, s4 = 2.f*s2*c2;
  float sa1, ca1; __sincosf((2.f * PI_F / 64.f) * (float)col, &sa1, &ca1);
  float ca2 = ca1*ca1 - sa1*sa1, sa2 = 2.f*sa1*ca1;
  float ca3 = ca2*ca1 - sa2*sa1, sa3 = sa2*ca1 + ca2*sa1;
  float ca4 = ca2*ca2 - sa2*sa2, sa4 = 2.f*sa2*ca2;
  f[0]=c1;  f[1]=c2;  f[2]=c3;  f[3]=c4;
  f[4]=s1;  f[5]=s2;  f[6]=s3;  f[7]=s4;
  f[8]=ca1; f[9]=ca2; f[10]=ca3; f[11]=ca4;
  f[12]=sa1; f[13]=sa2; f[14]=sa3; f[15]=sa4;
}

// ---------------- fused per-window kernel ----------------
__global__ __launch_bounds__(256) void win_kernel(
    const float* __restrict__ x, const float* __restrict__ D,
    const float* __restrict__ a_p, const float* __restrict__ b_p,
    const float* __restrict__ a_r, const float* __restrict__ b_r,
    const __hip_bfloat16* __restrict__ wq, const float* __restrict__ qkv_b,
    const __hip_bfloat16* __restrict__ pwb, const float* __restrict__ pb,
    float* __restrict__ out)
{
  // sX : x tile [64][256] bf16, XOR swizzle ((row&7)<<4) on 16B units
  // sStr: 4 wave-private 8KB stripes; per head, within-stripe lifetime:
  //   Q [64tok][32col]@0 -> qf ; K same@0 -> kf ; Km [64][16]@0 -> kmf ;
  //   V^T [32dim][64tok]@0 -> vf ; P [32][64]@0 (two ct-pair passes) ;
  //   O_headA @4096..8191, O_headB @0..4095 (persist to proj)
  // sQf: raw Fourier feats [64][32] (16 feats + 16 zeros), XOR ((row&3)<<4)
  __shared__ __align__(16) __hip_bfloat16 sX  [64 * 256];   // 32768 B
  __shared__ __align__(16) __hip_bfloat16 sStr[4 * 4096];   // 32768 B
  __shared__ __align__(16) __hip_bfloat16 sQf [64 * 32];    //  4096 B
  // total 69632 B -> 2 blocks/CU if VGPR alloc <= 256

  const int tid = threadIdx.x;
  const int lane = tid & 63, w = tid >> 6;          // 4 waves
  const int laneN = lane & 15, laneQ = lane >> 4;
  const int b = blockIdx.x;
  const floatx4 fzero = {0.f, 0.f, 0.f, 0.f};
  const short8 zero8 = {0, 0, 0, 0, 0, 0, 0, 0};

  char* xb = (char*)sX;
  char* sb = (char*)sStr + w * 8192;   // this wave's stripe

  // ---- phase 0: raw feats (per-lane, kept in regs) + stage x + sQf ----
  float f[16];
  fourier_feats(D[b * 64 + lane], lane & 7, f);

  const float4* xg = (const float4*)(x + (size_t)b * 16384);
  #pragma unroll 4
  for (int it = 0; it < 16; ++it) {
    int g = tid + it * 256;
    float4 v = xg[g];
    int t = g >> 6;
    int off = (t * 512 + (g & 63) * 8) ^ ((t & 7) << 4);
    short4v pk = { bfs(v.x), bfs(v.y), bfs(v.z), bfs(v.w) };
    *(short4v*)(xb + off) = pk;
  }
  if (tid < 64) {   // wave 0 writes shared raw-feat tile (16 feats | 16 zeros)
    int t = tid;
    uint4v q0 = { pk2(f[0],f[1]),  pk2(f[2],f[3]),  pk2(f[4],f[5]),   pk2(f[6],f[7]) };
    uint4v q1 = { pk2(f[8],f[9]),  pk2(f[10],f[11]),pk2(f[12],f[13]), pk2(f[14],f[15]) };
    uint4v zz = { 0u, 0u, 0u, 0u };
    char* qb = (char*)sQf;
    *(uint4v*)(qb + ((t * 64 +  0) ^ ((t & 3) << 4))) = q0;
    *(uint4v*)(qb + ((t * 64 + 16) ^ ((t & 3) << 4))) = q1;
    *(uint4v*)(qb + ((t * 64 + 32) ^ ((t & 3) << 4))) = zz;
    *(uint4v*)(qb + ((t * 64 + 48) ^ ((t & 3) << 4))) = zz;
  }
  __syncthreads();   // barrier A

  // ---- per-head processing: wave w handles heads w and w+4 ----
  for (int hi = 0; hi < 2; ++hi) {
    const int hh = w + hi * 4;

    const __hip_bfloat16* wqQ = wq + (size_t)(      hh*32 + laneN) * 256 + laneQ * 8;
    const __hip_bfloat16* wqK = wq + (size_t)(256 + hh*32 + laneN) * 256 + laneQ * 8;
    const __hip_bfloat16* wqV = wq + (size_t)(512 + hh*32 + laneN) * 256 + laneQ * 8;

    // ===== pass Q: GEMM (swapped: D = [col][token]), 32 accs =====
    short8 qf[4];
    {
      floatx4 Qa[4][2];
      #pragma unroll
      for (int mt = 0; mt < 4; ++mt) { Qa[mt][0]=fzero; Qa[mt][1]=fzero; }
      __builtin_amdgcn_s_setprio(1);
      #pragma unroll
      for (int kk = 0; kk < 8; ++kk) {
        short8 a4[4];
        #pragma unroll
        for (int mt = 0; mt < 4; ++mt) {
          int off = ((mt*16 + laneN) * 512 + kk*64 + laneQ*16) ^ ((laneN & 7) << 4);
          a4[mt] = *(const short8*)(xb + off);
        }
        #pragma unroll
        for (int ont = 0; ont < 2; ++ont) {
          short8 fq = *(const short8*)(wqQ + (size_t)ont*16*256 + kk*32);
          #pragma unroll
          for (int mt = 0; mt < 4; ++mt)
            Qa[mt][ont] = __builtin_amdgcn_mfma_f32_16x16x32_bf16(fq, a4[mt], Qa[mt][ont], 0, 0, 0);
        }
      }
      __builtin_amdgcn_s_setprio(0);
      float4 b0 = *(const float4*)&qkv_b[hh*32 +      laneQ*4];
      float4 b1 = *(const float4*)&qkv_b[hh*32 + 16 + laneQ*4];
      float qba[2][4] = {{b0.x,b0.y,b0.z,b0.w},{b1.x,b1.y,b1.z,b1.w}};
      #pragma unroll
      for (int mt = 0; mt < 4; ++mt)
        #pragma unroll
        for (int ont = 0; ont < 2; ++ont) {
          short4v pq;
          #pragma unroll
          for (int r = 0; r < 4; ++r)
            pq[r] = bfs((Qa[mt][ont][r] + qba[ont][r]) * SCALE_F);
          int off = ((mt*16 + laneN) * 64 + ont*32 + laneQ*8) ^ ((laneN & 3) << 4);
          *(short4v*)(sb + off) = pq;
        }
      #pragma unroll
      for (int ct = 0; ct < 4; ++ct)
        qf[ct] = *(const short8*)(sb + (((ct*16 + laneN) * 64 + laneQ*16) ^ ((laneN & 3) << 4)));
    }

    // ===== pass K: GEMM (swapped), 32 accs =====
    short8 kf[4];
    {
      floatx4 Ka[4][2];
      #pragma unroll
      for (int mt = 0; mt < 4; ++mt) { Ka[mt][0]=fzero; Ka[mt][1]=fzero; }
      __builtin_amdgcn_s_setprio(1);
      #pragma unroll
      for (int kk = 0; kk < 8; ++kk) {
        short8 a4[4];
        #pragma unroll
        for (int mt = 0; mt < 4; ++mt) {
          int off = ((mt*16 + laneN) * 512 + kk*64 + laneQ*16) ^ ((laneN & 7) << 4);
          a4[mt] = *(const short8*)(xb + off);
        }
        #pragma unroll
        for (int ont = 0; ont < 2; ++ont) {
          short8 fk = *(const short8*)(wqK + (size_t)ont*16*256 + kk*32);
          #pragma unroll
          for (int mt = 0; mt < 4; ++mt)
            Ka[mt][ont] = __builtin_amdgcn_mfma_f32_16x16x32_bf16(fk, a4[mt], Ka[mt][ont], 0, 0, 0);
        }
      }
      __builtin_amdgcn_s_setprio(0);
      float4 b0 = *(const float4*)&qkv_b[256 + hh*32 +      laneQ*4];
      float4 b1 = *(const float4*)&qkv_b[256 + hh*32 + 16 + laneQ*4];
      float kba[2][4] = {{b0.x,b0.y,b0.z,b0.w},{b1.x,b1.y,b1.z,b1.w}};
      #pragma unroll
      for (int mt = 0; mt < 4; ++mt)
        #pragma unroll
        for (int ont = 0; ont < 2; ++ont) {
          short4v pk;
          #pragma unroll
          for (int r = 0; r < 4; ++r)
            pk[r] = bfs(Ka[mt][ont][r] + kba[ont][r]);
          int off = ((mt*16 + laneN) * 64 + ont*32 + laneQ*8) ^ ((laneN & 3) << 4);
          *(short4v*)(sb + off) = pk;
        }
      #pragma unroll
      for (int rt = 0; rt < 4; ++rt)
        kf[rt] = *(const short8*)(sb + (((rt*16 + laneN) * 64 + laneQ*16) ^ ((laneN & 3) << 4)));
    }

    // ===== Km (per-head mixed feats) [64 tok][16] -> stripe 0..2047 =====
    short8 kmf[4];
    {
      float m0[4], m1[4], m2[4], m3[4];
      #pragma unroll
      for (int p = 0; p < 4; ++p) {
        float ar = a_r[(p+1)*8 + hh], br = b_r[p*8 + hh];
        float ap = a_p[(p+1)*8 + hh], bp = b_p[p*8 + hh];
        m0[p] = (ar*f[p]     + br*f[4+p])  * 0.25f;
        m1[p] = (ar*f[4+p]   - br*f[p])    * 0.25f;
        m2[p] = (ap*f[8+p]   - bp*f[12+p]) * 0.25f;
        m3[p] = (ap*f[12+p]  + bp*f[8+p])  * 0.25f;
      }
      uint4v k0 = { pk2(m0[0],m0[1]), pk2(m0[2],m0[3]), pk2(m1[0],m1[1]), pk2(m1[2],m1[3]) };
      uint4v k1 = { pk2(m2[0],m2[1]), pk2(m2[2],m2[3]), pk2(m3[0],m3[1]), pk2(m3[2],m3[3]) };
      *(uint4v*)(sb + lane * 32)      = k0;
      *(uint4v*)(sb + lane * 32 + 16) = k1;
      #pragma unroll
      for (int rt = 0; rt < 4; ++rt) {
        short8 t8 = *(const short8*)(sb + (rt*16 + laneN) * 32 + (laneQ & 1) * 16);
        kmf[rt] = (laneQ < 2) ? t8 : zero8;
      }
    }
    short8 qff[4];
    #pragma unroll
    for (int ct = 0; ct < 4; ++ct)
      qff[ct] = *(const short8*)((char*)sQf + (((ct*16 + laneN) * 64 + laneQ*16) ^ ((laneN & 3) << 4)));

    // ===== pass V: GEMM (unswapped: D = [token][vdim]), 32 accs =====
    short8 vf[2][2];
    {
      floatx4 Va[4][2];
      #pragma unroll
      for (int mt = 0; mt < 4; ++mt) { Va[mt][0]=fzero; Va[mt][1]=fzero; }
      __builtin_amdgcn_s_setprio(1);
      #pragma unroll
      for (int kk = 0; kk < 8; ++kk) {
        short8 a4[4];
        #pragma unroll
        for (int mt = 0; mt < 4; ++mt) {
          int off = ((mt*16 + laneN) * 512 + kk*64 + laneQ*16) ^ ((laneN & 7) << 4);
          a4[mt] = *(const short8*)(xb + off);
        }
        #pragma unroll
        for (int ont = 0; ont < 2; ++ont) {
          short8 fv = *(const short8*)(wqV + (size_t)ont*16*256 + kk*32);
          #pragma unroll
          for (int mt = 0; mt < 4; ++mt)
            Va[mt][ont] = __builtin_amdgcn_mfma_f32_16x16x32_bf16(a4[mt], fv, Va[mt][ont], 0, 0, 0);
        }
      }
      __builtin_amdgcn_s_setprio(0);
      // V^T -> stripe [32 dim][64 tok] (XOR (dim&7)<<4): lane holds 4
      // contiguous tokens at fixed dim -> packed b64 along tok.
      float bv0 = qkv_b[512 + hh*32 +      laneN];
      float bv1 = qkv_b[512 + hh*32 + 16 + laneN];
      #pragma unroll
      for (int mt = 0; mt < 4; ++mt)
        #pragma unroll
        for (int ont = 0; ont < 2; ++ont) {
          float bv = ont ? bv1 : bv0;
          short4v pv;
          #pragma unroll
          for (int r = 0; r < 4; ++r)
            pv[r] = bfs(Va[mt][ont][r] + bv);
          int off = ((ont*16 + laneN) * 128 + mt*32 + laneQ*8) ^ ((laneN & 7) << 4);
          *(short4v*)(sb + off) = pv;
        }
      #pragma unroll
      for (int ont = 0; ont < 2; ++ont)
        #pragma unroll
        for (int kb = 0; kb < 2; ++kb)
          vf[ont][kb] = *(const short8*)(sb + (((ont*16 + laneN) * 128 + kb*64 + laneQ*16) ^ ((laneN & 7) << 4)));
    }

    // ===== per ct-pair: S^T (16 MFMA) -> softmax -> P -> PV =====
    floatx4 Oa[2][4];
    #pragma unroll
    for (int cp = 0; cp < 2; ++cp) {
      floatx4 S[4][2];
      __builtin_amdgcn_s_setprio(1);
      #pragma unroll
      for (int rt = 0; rt < 4; ++rt)
        #pragma unroll
        for (int cc = 0; cc < 2; ++cc) {
          int ct = cp * 2 + cc;
          S[rt][cc] = __builtin_amdgcn_mfma_f32_16x16x32_bf16(kf[rt], qf[ct], fzero, 0, 0, 0);
          S[rt][cc] = __builtin_amdgcn_mfma_f32_16x16x32_bf16(kmf[rt], qff[ct], S[rt][cc], 0, 0, 0);
        }
      __builtin_amdgcn_s_setprio(0);

      // softmax over k (lane-local rt,r + shfl_xor 16/32)
      float inv2[2];
      #pragma unroll
      for (int cc = 0; cc < 2; ++cc) {
        float mx = S[0][cc][0];
        #pragma unroll
        for (int rt = 0; rt < 4; ++rt)
          #pragma unroll
          for (int r = 0; r < 4; ++r)
            mx = fmaxf(mx, S[rt][cc][r]);
        mx = fmaxf(mx, __shfl_xor(mx, 16));
        mx = fmaxf(mx, __shfl_xor(mx, 32));
        float sum = 0.f;
        #pragma unroll
        for (int rt = 0; rt < 4; ++rt)
          #pragma unroll
          for (int r = 0; r < 4; ++r) {
            S[rt][cc][r] = __expf(S[rt][cc][r] - mx);
            sum += S[rt][cc][r];
          }
        sum += __shfl_xor(sum, 16);
        sum += __shfl_xor(sum, 32);
        inv2[cc] = __builtin_amdgcn_rcpf(sum);
      }

      // P -> stripe [32 q][64 k] (XOR (row&7)<<4)
      #pragma unroll
      for (int cc = 0; cc < 2; ++cc)
        #pragma unroll
        for (int rt = 0; rt < 4; ++rt) {
          short4v pp;
          #pragma unroll
          for (int r = 0; r < 4; ++r)
            pp[r] = bfs(S[rt][cc][r] * inv2[cc]);
          int off = ((cc*16 + laneN) * 128 + rt*32 + laneQ*8) ^ ((laneN & 7) << 4);
          *(short4v*)(sb + off) = pp;
        }

      // PV (operand-swapped: D = [dim][q-token])
      __builtin_amdgcn_s_setprio(1);
      #pragma unroll
      for (int cc = 0; cc < 2; ++cc) {
        int ct = cp * 2 + cc;
        short8 pf0 = *(const short8*)(sb + (((cc*16 + laneN) * 128 +  0 + laneQ*16) ^ ((laneN & 7) << 4)));
        short8 pf1 = *(const short8*)(sb + (((cc*16 + laneN) * 128 + 64 + laneQ*16) ^ ((laneN & 7) << 4)));
        #pragma unroll
        for (int ont = 0; ont < 2; ++ont) {
          Oa[ont][ct] = __builtin_amdgcn_mfma_f32_16x16x32_bf16(vf[ont][0], pf0, fzero, 0, 0, 0);
          Oa[ont][ct] = __builtin_amdgcn_mfma_f32_16x16x32_bf16(vf[ont][1], pf1, Oa[ont][ct], 0, 0, 0);
        }
      }
      __builtin_amdgcn_s_setprio(0);
    }

    // ===== O -> stripe [64 tok][32 col] (headA @4096, headB @0) =====
    {
      int obase = hi ? 0 : 4096;
      #pragma unroll
      for (int ont = 0; ont < 2; ++ont)
        #pragma unroll
        for (int ct = 0; ct < 4; ++ct) {
          short4v po;
          #pragma unroll
          for (int r = 0; r < 4; ++r)
            po[r] = bfs(Oa[ont][ct][r]);
          int off = obase + (((ct*16 + laneN) * 64 + ont*32 + laneQ*8) ^ ((laneN & 3) << 4));
          *(short4v*)(sb + off) = po;
        }
    }
  }
  __syncthreads();   // barrier B — all O tiles parked in stripes

  // ---- proj GEMM: wave w owns out cols [64w, 64w+64) ----
  floatx4 pacc[4][4];
  #pragma unroll
  for (int mt = 0; mt < 4; ++mt)
    #pragma unroll
    for (int n = 0; n < 4; ++n) pacc[mt][n] = fzero;

  const __hip_bfloat16* pwr = pwb + (size_t)(w*64 + laneN) * 256 + laneQ * 8;
  #pragma unroll
  for (int kk = 0; kk < 8; ++kk) {        // kk == head index (32 dims each)
    char* ob = (char*)sStr + (kk & 3) * 8192 + ((kk < 4) ? 4096 : 0);
    short8 pa[4];
    #pragma unroll
    for (int mt = 0; mt < 4; ++mt)
      pa[mt] = *(const short8*)(ob + (((mt*16 + laneN) * 64 + laneQ*16) ^ ((laneN & 3) << 4)));
    short8 pw4[4];
    #pragma unroll
    for (int n = 0; n < 4; ++n)
      pw4[n] = *(const short8*)(pwr + (size_t)n*16*256 + kk*32);
    __builtin_amdgcn_s_setprio(1);
    #pragma unroll
    for (int mt = 0; mt < 4; ++mt)
      #pragma unroll
      for (int n = 0; n < 4; ++n)
        pacc[mt][n] = __builtin_amdgcn_mfma_f32_16x16x32_bf16(pw4[n], pa[mt], pacc[mt][n], 0, 0, 0);
    __builtin_amdgcn_s_setprio(0);
  }

  float* og = out + (size_t)b * 16384;
  #pragma unroll
  for (int n = 0; n < 4; ++n) {
    float4 b4 = *(const float4*)&pb[w*64 + n*16 + laneQ*4];
    #pragma unroll
    for (int mt = 0; mt < 4; ++mt) {
      float4 o4;
      o4.x = pacc[mt][n][0] + b4.x;
      o4.y = pacc[mt][n][1] + b4.y;
      o4.z = pacc[mt][n][2] + b4.z;
      o4.w = pacc[mt][n][3] + b4.w;
      *(float4*)&og[(mt*16 + laneN) * 256 + w*64 + n*16 + laneQ*4] = o4;
    }
  }
}

extern "C" void kernel_launch(void* const* d_in, const int* in_sizes, int n_in,
                              void* d_out, int out_size, void* d_ws, size_t ws_size,
                              hipStream_t stream) {
  const float* x      = (const float*)d_in[0];
  const float* D      = (const float*)d_in[1];
  const float* a_p    = (const float*)d_in[2];
  const float* b_p    = (const float*)d_in[3];
  const float* a_r    = (const float*)d_in[4];
  const float* b_r    = (const float*)d_in[5];
  const float* qkv_w  = (const float*)d_in[6];
  const float* qkv_b  = (const float*)d_in[7];
  const float* proj_w = (const float*)d_in[8];
  const float* proj_b = (const float*)d_in[9];

  __hip_bfloat16* wq  = (__hip_bfloat16*)d_ws;   // 196608 bf16 (qkv_w)
  __hip_bfloat16* pwb = wq + 196608;             // 65536 bf16 (proj_w)
  float* out = (float*)d_out;

  prep_kernel<<<256, 256, 0, stream>>>(qkv_w, proj_w, wq);
  win_kernel<<<1024, 256, 0, stream>>>(x, D, a_p, b_p, a_r, b_r, wq, qkv_b,
                                       pwb, proj_b, out);
}

// Round 8
// 231.340 us; speedup vs baseline: 1.0553x; 1.0553x over previous
//
#include <hip/hip_runtime.h>
#include <hip/hip_bf16.h>

// WindowAttention — r11b: resubmit of r11 (container infra failure, no data).
// Decisive 2-blocks/CU test. 8 waves x 1 head (r0's parallelism), LDS exactly
// 64 KB (sX 32K + 8 x 4KB stripes, no sQf), VGPR forced <=128 via
// __launch_bounds__(512,4) with structure shaped to ~124 peak live regs:
// per-ct attention (S[4]), O packed to bf16 immediately, f[16] recomputed,
// per-pass acc <=32. O parks into sX (x dead after V-pass). 3 barriers;
// waves run independently from barrier A through attention.
// All LDS address patterns byte-identical to r10 (verified passing).

using short8  = __attribute__((ext_vector_type(8))) short;
using short4v = __attribute__((ext_vector_type(4))) short;
using floatx4 = __attribute__((ext_vector_type(4))) float;
using uint4v  = __attribute__((ext_vector_type(4))) unsigned int;
using uint2v  = __attribute__((ext_vector_type(2))) unsigned int;

#define PI_F    3.14159265358979323846f
#define SCALE_F 0.17677669529663687f   // 32^-0.5

__device__ __forceinline__ short bfs(float x) {
  __hip_bfloat16 h = __float2bfloat16(x);
  return __builtin_bit_cast(short, h);
}

__device__ __forceinline__ unsigned pk2(float a, float b) {
  unsigned lo = (unsigned short)bfs(a);
  unsigned hi = (unsigned short)bfs(b);
  return lo | (hi << 16);
}

// ---------------- kernel 1: weights fp32 -> bf16 into ws ----------------
__global__ void prep_kernel(const float* __restrict__ qw,
                            const float* __restrict__ pw,
                            __hip_bfloat16* __restrict__ dst) {
  int g = blockIdx.x * 256 + threadIdx.x;  // 65536 threads, one float4 each
  const float4* src;
  __hip_bfloat16* d;
  if (g < 49152) { src = (const float4*)qw + g; d = dst + g * 4; }
  else { int g2 = g - 49152; src = (const float4*)pw + g2; d = dst + 196608 + g2 * 4; }
  float4 v = *src;
  d[0] = __float2bfloat16(v.x);
  d[1] = __float2bfloat16(v.y);
  d[2] = __float2bfloat16(v.z);
  d[3] = __float2bfloat16(v.w);
}

__device__ __forceinline__ void fourier_feats(float dv, int col, float* f) {
  float s1, c1; __sincosf(PI_F * dv, &s1, &c1);
  float c2 = c1*c1 - s1*s1, s2 = 2.f*s1*c1;
  float c3 = c2*c1 - s2*s1, s3 = s2*c1 + c2*s1;
  float c4 = c2*c2 - s2*s2, s4 = 2.f*s2*c2;
  float sa1, ca1; __sincosf((2.f * PI_F / 64.f) * (float)col, &sa1, &ca1);
  float ca2 = ca1*ca1 - sa1*sa1, sa2 = 2.f*sa1*ca1;
  float ca3 = ca2*ca1 - sa2*sa1, sa3 = sa2*ca1 + ca2*sa1;
  float ca4 = ca2*ca2 - sa2*sa2, sa4 = 2.f*sa2*ca2;
  f[0]=c1;  f[1]=c2;  f[2]=c3;  f[3]=c4;
  f[4]=s1;  f[5]=s2;  f[6]=s3;  f[7]=s4;
  f[8]=ca1; f[9]=ca2; f[10]=ca3; f[11]=ca4;
  f[12]=sa1; f[13]=sa2; f[14]=sa3; f[15]=sa4;
}

// ---------------- fused per-window kernel ----------------
__global__ __launch_bounds__(512, 4) void win_kernel(
    const float* __restrict__ x, const float* __restrict__ D,
    const float* __restrict__ a_p, const float* __restrict__ b_p,
    const float* __restrict__ a_r, const float* __restrict__ b_r,
    const __hip_bfloat16* __restrict__ wq, const float* __restrict__ qkv_b,
    const __hip_bfloat16* __restrict__ pwb, const float* __restrict__ pb,
    float* __restrict__ out)
{
  // sX : phase<=V: x tile [64][256] bf16, XOR ((row&7)<<4) on 16B units.
  //      phase>=park: 8 x per-head O tiles [64 tok][32 dim], 4KB each.
  // sStr: 8 wave-private 4KB stripes; sequential lifetime per wave:
  //   feats [64][64B] -> qff regs ; Q [64][32] -> qf ; K -> kf ;
  //   Km [64][32B] -> kmf ; V^T [32][64] -> vf ; P [16][64] per ct.
  __shared__ __align__(16) __hip_bfloat16 sX  [64 * 256];   // 32768 B
  __shared__ __align__(16) __hip_bfloat16 sStr[8 * 2048];   // 32768 B
  // total 65536 B -> 2 blocks/CU (LDS); VGPR<=128 -> 4 waves/SIMD

  const int tid = threadIdx.x;
  const int lane = tid & 63, w = tid >> 6;          // 8 waves, wave = head
  const int laneN = lane & 15, laneQ = lane >> 4;
  const int b = blockIdx.x;
  const floatx4 fzero = {0.f, 0.f, 0.f, 0.f};
  const short8 zero8 = {0, 0, 0, 0, 0, 0, 0, 0};

  char* xb = (char*)sX;
  char* sb = (char*)sStr + w * 4096;   // this wave's stripe

  // ---- phase 0: raw feats -> own stripe -> qff regs; stage x -> sX ----
  {
    float f[16];
    fourier_feats(D[b * 64 + lane], lane & 7, f);
    uint4v q0 = { pk2(f[0],f[1]),  pk2(f[2],f[3]),  pk2(f[4],f[5]),   pk2(f[6],f[7]) };
    uint4v q1 = { pk2(f[8],f[9]),  pk2(f[10],f[11]),pk2(f[12],f[13]), pk2(f[14],f[15]) };
    uint4v zz = { 0u, 0u, 0u, 0u };
    *(uint4v*)(sb + ((lane * 64 +  0) ^ ((lane & 3) << 4))) = q0;
    *(uint4v*)(sb + ((lane * 64 + 16) ^ ((lane & 3) << 4))) = q1;
    *(uint4v*)(sb + ((lane * 64 + 32) ^ ((lane & 3) << 4))) = zz;
    *(uint4v*)(sb + ((lane * 64 + 48) ^ ((lane & 3) << 4))) = zz;
  }
  const float4* xg = (const float4*)(x + (size_t)b * 16384);
  #pragma unroll
  for (int it = 0; it < 8; ++it) {
    int g = tid + it * 512;
    float4 v = xg[g];
    int t = g >> 6;
    int off = (t * 512 + (g & 63) * 8) ^ ((t & 7) << 4);
    short4v pk = { bfs(v.x), bfs(v.y), bfs(v.z), bfs(v.w) };
    *(short4v*)(xb + off) = pk;
  }
  short8 qff[4];   // raw-feat frags (k=32..63 of Q-ext), held
  #pragma unroll
  for (int ct = 0; ct < 4; ++ct)
    qff[ct] = *(const short8*)(sb + (((ct*16 + laneN) * 64 + laneQ*16) ^ ((laneN & 3) << 4)));
  __syncthreads();   // barrier A

  const int hh = w;
  const __hip_bfloat16* wqQ = wq + (size_t)(      hh*32 + laneN) * 256 + laneQ * 8;
  const __hip_bfloat16* wqK = wq + (size_t)(256 + hh*32 + laneN) * 256 + laneQ * 8;
  const __hip_bfloat16* wqV = wq + (size_t)(512 + hh*32 + laneN) * 256 + laneQ * 8;

  // ===== pass Q: GEMM (swapped: D = [col][token]), 32 accs =====
  short8 qf[4];
  {
    floatx4 Qa[4][2];
    #pragma unroll
    for (int mt = 0; mt < 4; ++mt) { Qa[mt][0]=fzero; Qa[mt][1]=fzero; }
    __builtin_amdgcn_s_setprio(1);
    #pragma unroll
    for (int kk = 0; kk < 8; ++kk) {
      short8 a4[4];
      #pragma unroll
      for (int mt = 0; mt < 4; ++mt) {
        int off = ((mt*16 + laneN) * 512 + kk*64 + laneQ*16) ^ ((laneN & 7) << 4);
        a4[mt] = *(const short8*)(xb + off);
      }
      #pragma unroll
      for (int ont = 0; ont < 2; ++ont) {
        short8 fq = *(const short8*)(wqQ + (size_t)ont*16*256 + kk*32);
        #pragma unroll
        for (int mt = 0; mt < 4; ++mt)
          Qa[mt][ont] = __builtin_amdgcn_mfma_f32_16x16x32_bf16(fq, a4[mt], Qa[mt][ont], 0, 0, 0);
      }
    }
    __builtin_amdgcn_s_setprio(0);
    float4 b0 = *(const float4*)&qkv_b[hh*32 +      laneQ*4];
    float4 b1 = *(const float4*)&qkv_b[hh*32 + 16 + laneQ*4];
    float qba[2][4] = {{b0.x,b0.y,b0.z,b0.w},{b1.x,b1.y,b1.z,b1.w}};
    #pragma unroll
    for (int mt = 0; mt < 4; ++mt)
      #pragma unroll
      for (int ont = 0; ont < 2; ++ont) {
        short4v pq;
        #pragma unroll
        for (int r = 0; r < 4; ++r)
          pq[r] = bfs((Qa[mt][ont][r] + qba[ont][r]) * SCALE_F);
        int off = ((mt*16 + laneN) * 64 + ont*32 + laneQ*8) ^ ((laneN & 3) << 4);
        *(short4v*)(sb + off) = pq;
      }
    #pragma unroll
    for (int ct = 0; ct < 4; ++ct)
      qf[ct] = *(const short8*)(sb + (((ct*16 + laneN) * 64 + laneQ*16) ^ ((laneN & 3) << 4)));
  }

  // ===== pass K: GEMM (swapped), 32 accs =====
  short8 kf[4];
  {
    floatx4 Ka[4][2];
    #pragma unroll
    for (int mt = 0; mt < 4; ++mt) { Ka[mt][0]=fzero; Ka[mt][1]=fzero; }
    __builtin_amdgcn_s_setprio(1);
    #pragma unroll
    for (int kk = 0; kk < 8; ++kk) {
      short8 a4[4];
      #pragma unroll
      for (int mt = 0; mt < 4; ++mt) {
        int off = ((mt*16 + laneN) * 512 + kk*64 + laneQ*16) ^ ((laneN & 7) << 4);
        a4[mt] = *(const short8*)(xb + off);
      }
      #pragma unroll
      for (int ont = 0; ont < 2; ++ont) {
        short8 fk = *(const short8*)(wqK + (size_t)ont*16*256 + kk*32);
        #pragma unroll
        for (int mt = 0; mt < 4; ++mt)
          Ka[mt][ont] = __builtin_amdgcn_mfma_f32_16x16x32_bf16(fk, a4[mt], Ka[mt][ont], 0, 0, 0);
      }
    }
    __builtin_amdgcn_s_setprio(0);
    float4 b0 = *(const float4*)&qkv_b[256 + hh*32 +      laneQ*4];
    float4 b1 = *(const float4*)&qkv_b[256 + hh*32 + 16 + laneQ*4];
    float kba[2][4] = {{b0.x,b0.y,b0.z,b0.w},{b1.x,b1.y,b1.z,b1.w}};
    #pragma unroll
    for (int mt = 0; mt < 4; ++mt)
      #pragma unroll
      for (int ont = 0; ont < 2; ++ont) {
        short4v pk;
        #pragma unroll
        for (int r = 0; r < 4; ++r)
          pk[r] = bfs(Ka[mt][ont][r] + kba[ont][r]);
        int off = ((mt*16 + laneN) * 64 + ont*32 + laneQ*8) ^ ((laneN & 3) << 4);
        *(short4v*)(sb + off) = pk;
      }
    #pragma unroll
    for (int rt = 0; rt < 4; ++rt)
      kf[rt] = *(const short8*)(sb + (((rt*16 + laneN) * 64 + laneQ*16) ^ ((laneN & 3) << 4)));
  }

  // ===== Km (recompute feats; per-head mixed) [64 tok][32B] -> stripe =====
  short8 kmf[4];
  {
    float f[16];
    fourier_feats(D[b * 64 + lane], lane & 7, f);
    float m0[4], m1[4], m2[4], m3[4];
    #pragma unroll
    for (int p = 0; p < 4; ++p) {
      float ar = a_r[(p+1)*8 + hh], br = b_r[p*8 + hh];
      float ap = a_p[(p+1)*8 + hh], bp = b_p[p*8 + hh];
      m0[p] = (ar*f[p]     + br*f[4+p])  * 0.25f;
      m1[p] = (ar*f[4+p]   - br*f[p])    * 0.25f;
      m2[p] = (ap*f[8+p]   - bp*f[12+p]) * 0.25f;
      m3[p] = (ap*f[12+p]  + bp*f[8+p])  * 0.25f;
    }
    uint4v k0 = { pk2(m0[0],m0[1]), pk2(m0[2],m0[3]), pk2(m1[0],m1[1]), pk2(m1[2],m1[3]) };
    uint4v k1 = { pk2(m2[0],m2[1]), pk2(m2[2],m2[3]), pk2(m3[0],m3[1]), pk2(m3[2],m3[3]) };
    *(uint4v*)(sb + lane * 32)      = k0;
    *(uint4v*)(sb + lane * 32 + 16) = k1;
    #pragma unroll
    for (int rt = 0; rt < 4; ++rt) {
      short8 t8 = *(const short8*)(sb + (rt*16 + laneN) * 32 + (laneQ & 1) * 16);
      kmf[rt] = (laneQ < 2) ? t8 : zero8;
    }
  }

  // ===== pass V: GEMM (unswapped: D = [token][vdim]), 32 accs =====
  short8 vf[2][2];
  {
    floatx4 Va[4][2];
    #pragma unroll
    for (int mt = 0; mt < 4; ++mt) { Va[mt][0]=fzero; Va[mt][1]=fzero; }
    __builtin_amdgcn_s_setprio(1);
    #pragma unroll
    for (int kk = 0; kk < 8; ++kk) {
      short8 a4[4];
      #pragma unroll
      for (int mt = 0; mt < 4; ++mt) {
        int off = ((mt*16 + laneN) * 512 + kk*64 + laneQ*16) ^ ((laneN & 7) << 4);
        a4[mt] = *(const short8*)(xb + off);
      }
      #pragma unroll
      for (int ont = 0; ont < 2; ++ont) {
        short8 fv = *(const short8*)(wqV + (size_t)ont*16*256 + kk*32);
        #pragma unroll
        for (int mt = 0; mt < 4; ++mt)
          Va[mt][ont] = __builtin_amdgcn_mfma_f32_16x16x32_bf16(a4[mt], fv, Va[mt][ont], 0, 0, 0);
      }
    }
    __builtin_amdgcn_s_setprio(0);
    float bv0 = qkv_b[512 + hh*32 +      laneN];
    float bv1 = qkv_b[512 + hh*32 + 16 + laneN];
    #pragma unroll
    for (int mt = 0; mt < 4; ++mt)
      #pragma unroll
      for (int ont = 0; ont < 2; ++ont) {
        float bv = ont ? bv1 : bv0;
        short4v pv;
        #pragma unroll
        for (int r = 0; r < 4; ++r)
          pv[r] = bfs(Va[mt][ont][r] + bv);
        int off = ((ont*16 + laneN) * 128 + mt*32 + laneQ*8) ^ ((laneN & 7) << 4);
        *(short4v*)(sb + off) = pv;
      }
    #pragma unroll
    for (int ont = 0; ont < 2; ++ont)
      #pragma unroll
      for (int kb = 0; kb < 2; ++kb)
        vf[ont][kb] = *(const short8*)(sb + (((ont*16 + laneN) * 128 + kb*64 + laneQ*16) ^ ((laneN & 7) << 4)));
  }

  // ===== per-ct: S^T (8 MFMA) -> softmax -> P (2KB) -> PV -> pack O =====
  unsigned opk[2][4][2];   // packed bf16 O, static-indexed (unrolled)
  #pragma unroll
  for (int ct = 0; ct < 4; ++ct) {
    floatx4 S[4];
    __builtin_amdgcn_s_setprio(1);
    #pragma unroll
    for (int rt = 0; rt < 4; ++rt) {
      S[rt] = __builtin_amdgcn_mfma_f32_16x16x32_bf16(kf[rt], qf[ct], fzero, 0, 0, 0);
      S[rt] = __builtin_amdgcn_mfma_f32_16x16x32_bf16(kmf[rt], qff[ct], S[rt], 0, 0, 0);
    }
    __builtin_amdgcn_s_setprio(0);

    float mx = S[0][0];
    #pragma unroll
    for (int rt = 0; rt < 4; ++rt)
      #pragma unroll
      for (int r = 0; r < 4; ++r)
        mx = fmaxf(mx, S[rt][r]);
    mx = fmaxf(mx, __shfl_xor(mx, 16));
    mx = fmaxf(mx, __shfl_xor(mx, 32));
    float sum = 0.f;
    #pragma unroll
    for (int rt = 0; rt < 4; ++rt)
      #pragma unroll
      for (int r = 0; r < 4; ++r) {
        S[rt][r] = __expf(S[rt][r] - mx);
        sum += S[rt][r];
      }
    sum += __shfl_xor(sum, 16);
    sum += __shfl_xor(sum, 32);
    float inv = __builtin_amdgcn_rcpf(sum);

    #pragma unroll
    for (int rt = 0; rt < 4; ++rt) {
      short4v pp;
      #pragma unroll
      for (int r = 0; r < 4; ++r)
        pp[r] = bfs(S[rt][r] * inv);
      int off = (laneN * 128 + rt*32 + laneQ*8) ^ ((laneN & 7) << 4);
      *(short4v*)(sb + off) = pp;
    }
    short8 pf0 = *(const short8*)(sb + ((laneN * 128 +      laneQ*16) ^ ((laneN & 7) << 4)));
    short8 pf1 = *(const short8*)(sb + ((laneN * 128 + 64 + laneQ*16) ^ ((laneN & 7) << 4)));
    __builtin_amdgcn_s_setprio(1);
    floatx4 O0 = __builtin_amdgcn_mfma_f32_16x16x32_bf16(vf[0][0], pf0, fzero, 0, 0, 0);
    O0 = __builtin_amdgcn_mfma_f32_16x16x32_bf16(vf[0][1], pf1, O0, 0, 0, 0);
    floatx4 O1 = __builtin_amdgcn_mfma_f32_16x16x32_bf16(vf[1][0], pf0, fzero, 0, 0, 0);
    O1 = __builtin_amdgcn_mfma_f32_16x16x32_bf16(vf[1][1], pf1, O1, 0, 0, 0);
    __builtin_amdgcn_s_setprio(0);
    opk[0][ct][0] = pk2(O0[0], O0[1]);
    opk[0][ct][1] = pk2(O0[2], O0[3]);
    opk[1][ct][0] = pk2(O1[0], O1[1]);
    opk[1][ct][1] = pk2(O1[2], O1[3]);
  }

  __syncthreads();   // barrier B1 — all x reads done; sX becomes O park
  #pragma unroll
  for (int ont = 0; ont < 2; ++ont)
    #pragma unroll
    for (int ct = 0; ct < 4; ++ct) {
      uint2v po = { opk[ont][ct][0], opk[ont][ct][1] };
      int off = w * 4096 + (((ct*16 + laneN) * 64 + ont*32 + laneQ*8) ^ ((laneN & 3) << 4));
      *(uint2v*)(xb + off) = po;
    }
  __syncthreads();   // barrier B2

  // ---- proj GEMM: wave w owns out cols [32w, 32w+32) ----
  floatx4 pacc[4][2];
  #pragma unroll
  for (int mt = 0; mt < 4; ++mt) { pacc[mt][0] = fzero; pacc[mt][1] = fzero; }
  const __hip_bfloat16* pwr = pwb + (size_t)(w*32 + laneN) * 256 + laneQ * 8;
  #pragma unroll
  for (int kk = 0; kk < 8; ++kk) {        // kk == head index (32 dims each)
    char* ob = xb + kk * 4096;
    short8 pa[4];
    #pragma unroll
    for (int mt = 0; mt < 4; ++mt)
      pa[mt] = *(const short8*)(ob + (((mt*16 + laneN) * 64 + laneQ*16) ^ ((laneN & 3) << 4)));
    short8 pw4[2];
    #pragma unroll
    for (int n = 0; n < 2; ++n)
      pw4[n] = *(const short8*)(pwr + (size_t)n*16*256 + kk*32);
    __builtin_amdgcn_s_setprio(1);
    #pragma unroll
    for (int mt = 0; mt < 4; ++mt)
      #pragma unroll
      for (int n = 0; n < 2; ++n)
        pacc[mt][n] = __builtin_amdgcn_mfma_f32_16x16x32_bf16(pw4[n], pa[mt], pacc[mt][n], 0, 0, 0);
    __builtin_amdgcn_s_setprio(0);
  }

  float* og = out + (size_t)b * 16384;
  #pragma unroll
  for (int n = 0; n < 2; ++n) {
    int col0 = w * 32 + n * 16;
    float4 b4 = *(const float4*)&pb[col0 + laneQ * 4];
    #pragma unroll
    for (int mt = 0; mt < 4; ++mt) {
      float4 o4;
      o4.x = pacc[mt][n][0] + b4.x;
      o4.y = pacc[mt][n][1] + b4.y;
      o4.z = pacc[mt][n][2] + b4.z;
      o4.w = pacc[mt][n][3] + b4.w;
      *(float4*)&og[(mt*16 + laneN) * 256 + col0 + laneQ*4] = o4;
    }
  }
}

extern "C" void kernel_launch(void* const* d_in, const int* in_sizes, int n_in,
                              void* d_out, int out_size, void* d_ws, size_t ws_size,
                              hipStream_t stream) {
  const float* x      = (const float*)d_in[0];
  const float* D      = (const float*)d_in[1];
  const float* a_p    = (const float*)d_in[2];
  const float* b_p    = (const float*)d_in[3];
  const float* a_r    = (const float*)d_in[4];
  const float* b_r    = (const float*)d_in[5];
  const float* qkv_w  = (const float*)d_in[6];
  const float* qkv_b  = (const float*)d_in[7];
  const float* proj_w = (const float*)d_in[8];
  const float* proj_b = (const float*)d_in[9];

  __hip_bfloat16* wq  = (__hip_bfloat16*)d_ws;   // 196608 bf16 (qkv_w)
  __hip_bfloat16* pwb = wq + 196608;             // 65536 bf16 (proj_w)
  float* out = (float*)d_out;

  prep_kernel<<<256, 256, 0, stream>>>(qkv_w, proj_w, wq);
  win_kernel<<<1024, 512, 0, stream>>>(x, D, a_p, b_p, a_r, b_r, wq, qkv_b,
                                       pwb, proj_b, out);
}